// Round 2
// baseline (1219.707 us; speedup 1.0000x reference)
//
#include <hip/hip_runtime.h>
#include <hip/hip_bf16.h>

// Problem constants (B=2,S=2048,H=1024,I=2816,E=7,TOPK=2)
#define NTOK 4096         // B*S
#define HH 1024
#define II 2816
#define EE 7
#define SHARED_BASE 8192  // NTOK*TOPK routed slots, then NTOK shared slots
#define NSLOT 12288       // 8192 + 4096

typedef __bf16 bf16x8 __attribute__((ext_vector_type(8)));
typedef __bf16 bf16x4 __attribute__((ext_vector_type(4)));
typedef float  f32x4v __attribute__((ext_vector_type(4)));

// ---------------------------------------------------------------- cvt x->bf16
__global__ void cvt_x(const float* __restrict__ x, __bf16* __restrict__ xb) {
    int i = blockIdx.x * blockDim.x + threadIdx.x;   // 262144 threads
    const f32x4v* xv = (const f32x4v*)x;
    bf16x4* ov = (bf16x4*)xb;
    int base = i * 4;                                 // 4 float4 per thread
#pragma unroll
    for (int j = 0; j < 4; j++) {
        f32x4v f = xv[base + j];
        bf16x4 b;
        b[0] = (__bf16)f[0]; b[1] = (__bf16)f[1];
        b[2] = (__bf16)f[2]; b[3] = (__bf16)f[3];
        ov[base + j] = b;
    }
}

// ---------------------------------------------------------------- router
// One wave per token. fp64 accumulation so top-2 selection matches the
// reference even near ties.
__global__ void router_k(const float* __restrict__ x, const float* __restrict__ Wr,
                         float* __restrict__ logits, int* __restrict__ counts,
                         int* __restrict__ sel, float* __restrict__ wtop,
                         int* __restrict__ tlist, float* __restrict__ wlist) {
    int wave = threadIdx.x >> 6;
    int lane = threadIdx.x & 63;
    int t = blockIdx.x * 4 + wave;
    const float* xr = x + (size_t)t * HH;
    double acc[EE];
#pragma unroll
    for (int e = 0; e < EE; e++) acc[e] = 0.0;
    for (int j = 0; j < 16; j++) {
        int h = lane + j * 64;
        double xv = (double)xr[h];
#pragma unroll
        for (int e = 0; e < EE; e++) acc[e] += xv * (double)Wr[e * HH + h];
    }
#pragma unroll
    for (int e = 0; e < EE; e++) {
        for (int off = 32; off > 0; off >>= 1) acc[e] += __shfl_down(acc[e], off, 64);
    }
    if (lane == 0) {
        int e0 = 0;
        for (int e = 1; e < EE; e++) if (acc[e] > acc[e0]) e0 = e;
        int e1 = -1;
        for (int e = 0; e < EE; e++) {
            if (e == e0) continue;
            if (e1 < 0 || acc[e] > acc[e1]) e1 = e;
        }
        double w1 = exp(acc[e1] - acc[e0]);
        double s = 1.0 + w1;
        for (int e = 0; e < EE; e++) logits[(size_t)t * EE + e] = (float)acc[e];
        sel[2 * t] = e0; sel[2 * t + 1] = e1;
        wtop[2 * t] = (float)(1.0 / s); wtop[2 * t + 1] = (float)(w1 / s);
        atomicAdd(&counts[e0], 1);
        atomicAdd(&counts[e1], 1);
        tlist[SHARED_BASE + t] = t;
        wlist[SHARED_BASE + t] = 1.0f;
    }
}

// ---------------------------------------------------------------- finalize
__global__ void finalize_k(const int* __restrict__ counts, int* __restrict__ cursor,
                           int* __restrict__ nlist, int* __restrict__ offs) {
    if (threadIdx.x == 0 && blockIdx.x == 0) {
        int o = 0;
        for (int e = 0; e < EE; e++) {
            offs[e] = o; cursor[e] = o; nlist[e] = counts[e];
            o += counts[e];
        }
        offs[EE] = SHARED_BASE;
        nlist[EE] = NTOK;
        cursor[EE] = SHARED_BASE;
    }
}

// ---------------------------------------------------------------- scatter
__global__ void scatter_k(const int* __restrict__ sel, const float* __restrict__ wtop,
                          int* __restrict__ cursor, int* __restrict__ tlist,
                          float* __restrict__ wlist) {
    int t = blockIdx.x * blockDim.x + threadIdx.x;
    if (t >= NTOK) return;
#pragma unroll
    for (int j = 0; j < 2; j++) {
        int e = sel[2 * t + j];
        int slot = atomicAdd(&cursor[e], 1);
        tlist[slot] = t;
        wlist[slot] = wtop[2 * t + j];
    }
}

// ---------------------------------------------------------------- gate+up GEMM
// Block tile 128(M) x 64(N), BK=32, 4 waves as 2x2, wave tile 64x32.
// acc = 16 f32x4 = 64 regs total (g+u) -> target 3 waves/SIMD occupancy.
// grid.x = mtile (fastest) so concurrent blocks share the same B-tile in L2.
__global__ __launch_bounds__(256, 3) void gateup_k(
        const float* __restrict__ Wg, const float* __restrict__ Wu,
        const float* __restrict__ Wgs, const float* __restrict__ Wus,
        const __bf16* __restrict__ xb, __bf16* __restrict__ hbuf,
        const int* __restrict__ nlist, const int* __restrict__ offs,
        const int* __restrict__ tlist) {
    const int e = blockIdx.z;
    const int ne = nlist[e];
    const int mt = blockIdx.x;
    if (mt * 128 >= ne) return;
    const int nt = blockIdx.y;                        // 44 tiles of 64 along I
    const int base = offs[e];
    const float* wg = (e < EE) ? Wg + (size_t)e * II * HH : Wgs;
    const float* wu = (e < EE) ? Wu + (size_t)e * II * HH : Wus;

    __shared__ __bf16 As[128 * 32];   // 8 KB
    __shared__ __bf16 Bg[64 * 32];    // 4 KB
    __shared__ __bf16 Bu[64 * 32];    // 4 KB

    const int tid = threadIdx.x;
    // A staging: 512 16B vectors; thread handles v = tid, tid+256
    const int arow0 = tid >> 2, c8a = (tid & 3) * 8;
    const int arow1 = (tid + 256) >> 2;
    const int cl0 = min(mt * 128 + arow0, ne - 1);
    const int cl1 = min(mt * 128 + arow1, ne - 1);
    const __bf16* aptr0 = xb + (size_t)tlist[base + cl0] * HH + c8a;
    const __bf16* aptr1 = xb + (size_t)tlist[base + cl1] * HH + c8a;
    // B staging: 256 16B-dest vectors per matrix; thread handles v = tid
    const int brow = tid >> 2, c8b = (tid & 3) * 8;
    const size_t boff = (size_t)(nt * 64 + brow) * HH + c8b;

    const int wid = tid >> 6, lane = tid & 63;
    const int wm = wid >> 1, wn = wid & 1;
    const int l16 = lane & 15, quad = lane >> 4;

    f32x4v accg[4][2], accu[4][2];
#pragma unroll
    for (int i = 0; i < 4; i++)
#pragma unroll
        for (int j = 0; j < 2; j++) { accg[i][j] = (f32x4v)0.0f; accu[i][j] = (f32x4v)0.0f; }

    for (int k0 = 0; k0 < HH; k0 += 32) {
        __syncthreads();
        *(bf16x8*)&As[arow0 * 32 + c8a] = *(const bf16x8*)(aptr0 + k0);
        *(bf16x8*)&As[arow1 * 32 + c8a] = *(const bf16x8*)(aptr1 + k0);
        {
            f32x4v f0 = *(const f32x4v*)(wg + boff + k0);
            f32x4v f1 = *(const f32x4v*)(wg + boff + k0 + 4);
            bf16x8 b;
            b[0] = (__bf16)f0[0]; b[1] = (__bf16)f0[1]; b[2] = (__bf16)f0[2]; b[3] = (__bf16)f0[3];
            b[4] = (__bf16)f1[0]; b[5] = (__bf16)f1[1]; b[6] = (__bf16)f1[2]; b[7] = (__bf16)f1[3];
            *(bf16x8*)&Bg[brow * 32 + c8b] = b;
            f0 = *(const f32x4v*)(wu + boff + k0);
            f1 = *(const f32x4v*)(wu + boff + k0 + 4);
            b[0] = (__bf16)f0[0]; b[1] = (__bf16)f0[1]; b[2] = (__bf16)f0[2]; b[3] = (__bf16)f0[3];
            b[4] = (__bf16)f1[0]; b[5] = (__bf16)f1[1]; b[6] = (__bf16)f1[2]; b[7] = (__bf16)f1[3];
            *(bf16x8*)&Bu[brow * 32 + c8b] = b;
        }
        __syncthreads();
        bf16x8 a[4];
#pragma unroll
        for (int i = 0; i < 4; i++)
            a[i] = *(const bf16x8*)&As[(wm * 64 + i * 16 + l16) * 32 + quad * 8];
#pragma unroll
        for (int j = 0; j < 2; j++) {
            bf16x8 bg = *(const bf16x8*)&Bg[(wn * 32 + j * 16 + l16) * 32 + quad * 8];
            bf16x8 bu = *(const bf16x8*)&Bu[(wn * 32 + j * 16 + l16) * 32 + quad * 8];
#pragma unroll
            for (int i = 0; i < 4; i++) {
                accg[i][j] = __builtin_amdgcn_mfma_f32_16x16x32_bf16(a[i], bg, accg[i][j], 0, 0, 0);
                accu[i][j] = __builtin_amdgcn_mfma_f32_16x16x32_bf16(a[i], bu, accu[i][j], 0, 0, 0);
            }
        }
    }
    // epilogue: h = silu(g)*u -> bf16
#pragma unroll
    for (int i = 0; i < 4; i++) {
        const int mrow = mt * 128 + wm * 64 + i * 16 + quad * 4;
#pragma unroll
        for (int r = 0; r < 4; r++) {
            const int slot = mrow + r;
            if (slot < ne) {
                __bf16* hrow = hbuf + (size_t)(base + slot) * II + nt * 64 + wn * 32 + l16;
#pragma unroll
                for (int j = 0; j < 2; j++) {
                    float g = accg[i][j][r], u = accu[i][j][r];
                    float sgl = g / (1.0f + __expf(-g));
                    hrow[j * 16] = (__bf16)(sgl * u);
                }
            }
        }
    }
}

// ---------------------------------------------------------------- down proj
// Block tile 128(M) x 128(N), BK=32, wave tile 64x64, acc = 64 regs.
__global__ __launch_bounds__(256, 3) void down_k(
        const float* __restrict__ Wd, const float* __restrict__ Wds,
        const __bf16* __restrict__ hbuf, float* __restrict__ out,
        const int* __restrict__ nlist, const int* __restrict__ offs,
        const int* __restrict__ tlist, const float* __restrict__ wlist) {
    const int e = blockIdx.z;
    const int ne = nlist[e];
    const int mt = blockIdx.x;
    if (mt * 128 >= ne) return;
    const int nt = blockIdx.y;                        // 8 tiles of 128 along H
    const int base = offs[e];
    const float* wd = (e < EE) ? Wd + (size_t)e * HH * II : Wds;

    __shared__ __bf16 As[128 * 32];   // 8 KB
    __shared__ __bf16 Bs[128 * 32];   // 8 KB

    const int tid = threadIdx.x;
    const int arow0 = tid >> 2, c8 = (tid & 3) * 8;
    const int arow1 = (tid + 256) >> 2;
    const int cl0 = min(mt * 128 + arow0, ne - 1);
    const int cl1 = min(mt * 128 + arow1, ne - 1);
    const __bf16* aptr0 = hbuf + (size_t)(base + cl0) * II + c8;
    const __bf16* aptr1 = hbuf + (size_t)(base + cl1) * II + c8;
    const size_t boff0 = (size_t)(nt * 128 + arow0) * II + c8;
    const size_t boff1 = (size_t)(nt * 128 + arow1) * II + c8;

    const int wid = tid >> 6, lane = tid & 63;
    const int wm = wid >> 1, wn = wid & 1;
    const int l16 = lane & 15, quad = lane >> 4;

    f32x4v acc[4][4];
#pragma unroll
    for (int i = 0; i < 4; i++)
#pragma unroll
        for (int j = 0; j < 4; j++) acc[i][j] = (f32x4v)0.0f;

    for (int k0 = 0; k0 < II; k0 += 32) {
        __syncthreads();
        *(bf16x8*)&As[arow0 * 32 + c8] = *(const bf16x8*)(aptr0 + k0);
        *(bf16x8*)&As[arow1 * 32 + c8] = *(const bf16x8*)(aptr1 + k0);
        {
            f32x4v f0 = *(const f32x4v*)(wd + boff0 + k0);
            f32x4v f1 = *(const f32x4v*)(wd + boff0 + k0 + 4);
            bf16x8 b;
            b[0] = (__bf16)f0[0]; b[1] = (__bf16)f0[1]; b[2] = (__bf16)f0[2]; b[3] = (__bf16)f0[3];
            b[4] = (__bf16)f1[0]; b[5] = (__bf16)f1[1]; b[6] = (__bf16)f1[2]; b[7] = (__bf16)f1[3];
            *(bf16x8*)&Bs[arow0 * 32 + c8] = b;
            f0 = *(const f32x4v*)(wd + boff1 + k0);
            f1 = *(const f32x4v*)(wd + boff1 + k0 + 4);
            b[0] = (__bf16)f0[0]; b[1] = (__bf16)f0[1]; b[2] = (__bf16)f0[2]; b[3] = (__bf16)f0[3];
            b[4] = (__bf16)f1[0]; b[5] = (__bf16)f1[1]; b[6] = (__bf16)f1[2]; b[7] = (__bf16)f1[3];
            *(bf16x8*)&Bs[arow1 * 32 + c8] = b;
        }
        __syncthreads();
        bf16x8 a[4];
#pragma unroll
        for (int i = 0; i < 4; i++)
            a[i] = *(const bf16x8*)&As[(wm * 64 + i * 16 + l16) * 32 + quad * 8];
#pragma unroll
        for (int j = 0; j < 4; j++) {
            bf16x8 b = *(const bf16x8*)&Bs[(wn * 64 + j * 16 + l16) * 32 + quad * 8];
#pragma unroll
            for (int i = 0; i < 4; i++)
                acc[i][j] = __builtin_amdgcn_mfma_f32_16x16x32_bf16(a[i], b, acc[i][j], 0, 0, 0);
        }
    }
    // epilogue: out[token] += w_slot * acc
#pragma unroll
    for (int i = 0; i < 4; i++) {
        const int mrow = mt * 128 + wm * 64 + i * 16 + quad * 4;
#pragma unroll
        for (int r = 0; r < 4; r++) {
            const int slot = mrow + r;
            if (slot < ne) {
                const int idx = base + slot;
                const int tok = tlist[idx];
                const float w = wlist[idx];
                float* orow = out + (size_t)tok * HH + nt * 128 + wn * 64 + l16;
#pragma unroll
                for (int j = 0; j < 4; j++)
                    atomicAdd(&orow[j * 16], w * acc[i][j][r]);
            }
        }
    }
}

// ---------------------------------------------------------------- launch
extern "C" void kernel_launch(void* const* d_in, const int* in_sizes, int n_in,
                              void* d_out, int out_size, void* d_ws, size_t ws_size,
                              hipStream_t stream) {
    const float* x   = (const float*)d_in[0];
    const float* Wgs = (const float*)d_in[1];
    const float* Wus = (const float*)d_in[2];
    const float* Wds = (const float*)d_in[3];
    const float* Wg  = (const float*)d_in[4];
    const float* Wu  = (const float*)d_in[5];
    const float* Wd  = (const float*)d_in[6];
    const float* Wr  = (const float*)d_in[7];
    float* out = (float*)d_out;                        // [NTOK][HH]
    float* logits = out + (size_t)NTOK * HH;           // [NTOK][EE]

    // workspace layout (~78 MB)
    char* ws = (char*)d_ws;
    __bf16* hbuf = (__bf16*)ws;                                    // NSLOT*II bf16
    __bf16* xb   = (__bf16*)(ws + (size_t)NSLOT * II * 2);         // NTOK*HH bf16
    char* meta   = ws + (size_t)NSLOT * II * 2 + (size_t)NTOK * HH * 2;
    int* counts = (int*)meta;            // 8
    int* cursor = counts + 8;            // 8
    int* nlist  = cursor + 8;            // 8
    int* offs   = nlist + 8;             // 8
    int* sel    = offs + 8;              // 2*NTOK
    int* tlist  = sel + 2 * NTOK;        // NSLOT
    float* wtop = (float*)(tlist + NSLOT);   // 2*NTOK
    float* wlist = wtop + 2 * NTOK;          // NSLOT

    hipMemsetAsync(counts, 0, 8 * sizeof(int), stream);
    hipMemsetAsync(out, 0, (size_t)NTOK * HH * sizeof(float), stream);

    cvt_x<<<1024, 256, 0, stream>>>(x, xb);
    router_k<<<NTOK / 4, 256, 0, stream>>>(x, Wr, logits, counts, sel, wtop, tlist, wlist);
    finalize_k<<<1, 64, 0, stream>>>(counts, cursor, nlist, offs);
    scatter_k<<<NTOK / 256, 256, 0, stream>>>(sel, wtop, cursor, tlist, wlist);
    gateup_k<<<dim3(32, II / 64, EE + 1), 256, 0, stream>>>(Wg, Wu, Wgs, Wus, xb, hbuf,
                                                            nlist, offs, tlist);
    down_k<<<dim3(32, HH / 128, EE + 1), 256, 0, stream>>>(Wd, Wds, hbuf, out,
                                                           nlist, offs, tlist, wlist);
}

// Round 3
// 822.097 us; speedup vs baseline: 1.4837x; 1.4837x over previous
//
#include <hip/hip_runtime.h>
#include <hip/hip_bf16.h>

// Problem constants (B=2,S=2048,H=1024,I=2816,E=7,TOPK=2)
#define NTOK 4096         // B*S
#define HH 1024
#define II 2816
#define EE 7
#define SHARED_BASE 8192  // NTOK*TOPK routed slots, then NTOK shared slots
#define NSLOT 12288       // 8192 + 4096

typedef __bf16 bf16x8 __attribute__((ext_vector_type(8)));
typedef __bf16 bf16x4 __attribute__((ext_vector_type(4)));
typedef float  f32x4v __attribute__((ext_vector_type(4)));

// ---------------------------------------------------------------- cvt x->bf16
__global__ void cvt_x(const float* __restrict__ x, __bf16* __restrict__ xb) {
    int i = blockIdx.x * blockDim.x + threadIdx.x;   // 262144 threads
    const f32x4v* xv = (const f32x4v*)x;
    bf16x4* ov = (bf16x4*)xb;
    int base = i * 4;                                 // 4 float4 per thread
#pragma unroll
    for (int j = 0; j < 4; j++) {
        f32x4v f = xv[base + j];
        bf16x4 b;
        b[0] = (__bf16)f[0]; b[1] = (__bf16)f[1];
        b[2] = (__bf16)f[2]; b[3] = (__bf16)f[3];
        ov[base + j] = b;
    }
}

// ---------------------------------------------------------------- router
// One wave per token. fp64 accumulation so top-2 selection matches the
// reference even near ties.
__global__ void router_k(const float* __restrict__ x, const float* __restrict__ Wr,
                         float* __restrict__ logits, int* __restrict__ counts,
                         int* __restrict__ sel, float* __restrict__ wtop,
                         int* __restrict__ tlist, float* __restrict__ wlist) {
    int wave = threadIdx.x >> 6;
    int lane = threadIdx.x & 63;
    int t = blockIdx.x * 4 + wave;
    const float* xr = x + (size_t)t * HH;
    double acc[EE];
#pragma unroll
    for (int e = 0; e < EE; e++) acc[e] = 0.0;
    for (int j = 0; j < 16; j++) {
        int h = lane + j * 64;
        double xv = (double)xr[h];
#pragma unroll
        for (int e = 0; e < EE; e++) acc[e] += xv * (double)Wr[e * HH + h];
    }
#pragma unroll
    for (int e = 0; e < EE; e++) {
        for (int off = 32; off > 0; off >>= 1) acc[e] += __shfl_down(acc[e], off, 64);
    }
    if (lane == 0) {
        int e0 = 0;
        for (int e = 1; e < EE; e++) if (acc[e] > acc[e0]) e0 = e;
        int e1 = -1;
        for (int e = 0; e < EE; e++) {
            if (e == e0) continue;
            if (e1 < 0 || acc[e] > acc[e1]) e1 = e;
        }
        double w1 = exp(acc[e1] - acc[e0]);
        double s = 1.0 + w1;
        for (int e = 0; e < EE; e++) logits[(size_t)t * EE + e] = (float)acc[e];
        sel[2 * t] = e0; sel[2 * t + 1] = e1;
        wtop[2 * t] = (float)(1.0 / s); wtop[2 * t + 1] = (float)(w1 / s);
        atomicAdd(&counts[e0], 1);
        atomicAdd(&counts[e1], 1);
        tlist[SHARED_BASE + t] = t;
        wlist[SHARED_BASE + t] = 1.0f;
    }
}

// ---------------------------------------------------------------- finalize
__global__ void finalize_k(const int* __restrict__ counts, int* __restrict__ cursor,
                           int* __restrict__ nlist, int* __restrict__ offs) {
    if (threadIdx.x == 0 && blockIdx.x == 0) {
        int o = 0;
        for (int e = 0; e < EE; e++) {
            offs[e] = o; cursor[e] = o; nlist[e] = counts[e];
            o += counts[e];
        }
        offs[EE] = SHARED_BASE;
        nlist[EE] = NTOK;
        cursor[EE] = SHARED_BASE;
    }
}

// ---------------------------------------------------------------- scatter
__global__ void scatter_k(const int* __restrict__ sel, const float* __restrict__ wtop,
                          int* __restrict__ cursor, int* __restrict__ tlist,
                          float* __restrict__ wlist) {
    int t = blockIdx.x * blockDim.x + threadIdx.x;
    if (t >= NTOK) return;
#pragma unroll
    for (int j = 0; j < 2; j++) {
        int e = sel[2 * t + j];
        int slot = atomicAdd(&cursor[e], 1);
        tlist[slot] = t;
        wlist[slot] = wtop[2 * t + j];
    }
}

// ---------------------------------------------------------------- gate+up GEMM
// Block tile 128(M) x 64(N), BK=32, 4 waves (2x2), wave tile 64x32 per output.
// Register-prefetch pipeline: K-step k+1's global loads issue right after
// step k's LDS stores and land during the MFMA phase (latency hidden).
// XCD swizzle: all m-tiles of N-panel nt have block ids == nt (mod 8) so they
// share one XCD's L2 -> weight panel fetched from HBM once (panel 0.5 MB fp32,
// 6 panels/XCD = 3 MB < 4 MB L2).
__global__ __launch_bounds__(256, 3) void gateup_k(
        const float* __restrict__ Wg, const float* __restrict__ Wu,
        const float* __restrict__ Wgs, const float* __restrict__ Wus,
        const __bf16* __restrict__ xb, __bf16* __restrict__ hbuf,
        const int* __restrict__ nlist, const int* __restrict__ offs,
        const int* __restrict__ tlist) {
    const int e = blockIdx.z;
    const int ne = nlist[e];
    const int bx = blockIdx.x;                 // [0,1536) per expert (48 nt' x 32 mt)
    const int nt = (bx & 7) + 8 * (bx >> 8);   // nt' in [0,48); XCD = nt % 8
    const int mt = (bx >> 3) & 31;
    if (nt >= II / 64) return;                 // 44 real panels
    if (mt * 128 >= ne) return;
    const int base = offs[e];
    const float* wg = (e < EE) ? Wg + (size_t)e * II * HH : Wgs;
    const float* wu = (e < EE) ? Wu + (size_t)e * II * HH : Wus;

    __shared__ __bf16 As[128 * 32];   // 8 KB
    __shared__ __bf16 Bg[64 * 32];    // 4 KB
    __shared__ __bf16 Bu[64 * 32];    // 4 KB

    const int tid = threadIdx.x;
    const int arow0 = tid >> 2, c8 = (tid & 3) * 8;
    const int arow1 = arow0 + 64;
    const int cl0 = min(mt * 128 + arow0, ne - 1);
    const int cl1 = min(mt * 128 + arow1, ne - 1);
    const __bf16* aptr0 = xb + (size_t)tlist[base + cl0] * HH + c8;
    const __bf16* aptr1 = xb + (size_t)tlist[base + cl1] * HH + c8;
    const int brow = tid >> 2;                 // B dest row [0,64)
    const size_t boff = (size_t)(nt * 64 + brow) * HH + c8;

    const int wid = tid >> 6, lane = tid & 63;
    const int wm = wid >> 1, wn = wid & 1;
    const int l16 = lane & 15, quad = lane >> 4;

    f32x4v accg[4][2], accu[4][2];
#pragma unroll
    for (int i = 0; i < 4; i++)
#pragma unroll
        for (int j = 0; j < 2; j++) { accg[i][j] = (f32x4v)0.0f; accu[i][j] = (f32x4v)0.0f; }

    // prefetch K-step 0
    bf16x8 aR0 = *(const bf16x8*)aptr0;
    bf16x8 aR1 = *(const bf16x8*)aptr1;
    f32x4v g0 = *(const f32x4v*)(wg + boff);
    f32x4v g1 = *(const f32x4v*)(wg + boff + 4);
    f32x4v u0 = *(const f32x4v*)(wu + boff);
    f32x4v u1 = *(const f32x4v*)(wu + boff + 4);

    for (int k0 = 0; k0 < HH; k0 += 32) {
        bf16x8 bgv, buv;
        bgv[0] = (__bf16)g0[0]; bgv[1] = (__bf16)g0[1]; bgv[2] = (__bf16)g0[2]; bgv[3] = (__bf16)g0[3];
        bgv[4] = (__bf16)g1[0]; bgv[5] = (__bf16)g1[1]; bgv[6] = (__bf16)g1[2]; bgv[7] = (__bf16)g1[3];
        buv[0] = (__bf16)u0[0]; buv[1] = (__bf16)u0[1]; buv[2] = (__bf16)u0[2]; buv[3] = (__bf16)u0[3];
        buv[4] = (__bf16)u1[0]; buv[5] = (__bf16)u1[1]; buv[6] = (__bf16)u1[2]; buv[7] = (__bf16)u1[3];
        __syncthreads();
        *(bf16x8*)&As[arow0 * 32 + c8] = aR0;
        *(bf16x8*)&As[arow1 * 32 + c8] = aR1;
        *(bf16x8*)&Bg[brow * 32 + c8] = bgv;
        *(bf16x8*)&Bu[brow * 32 + c8] = buv;
        if (k0 + 32 < HH) {      // prefetch next K-step; lands during MFMA phase
            aR0 = *(const bf16x8*)(aptr0 + k0 + 32);
            aR1 = *(const bf16x8*)(aptr1 + k0 + 32);
            g0 = *(const f32x4v*)(wg + boff + k0 + 32);
            g1 = *(const f32x4v*)(wg + boff + k0 + 36);
            u0 = *(const f32x4v*)(wu + boff + k0 + 32);
            u1 = *(const f32x4v*)(wu + boff + k0 + 36);
        }
        __syncthreads();
        bf16x8 a[4];
#pragma unroll
        for (int i = 0; i < 4; i++)
            a[i] = *(const bf16x8*)&As[(wm * 64 + i * 16 + l16) * 32 + quad * 8];
#pragma unroll
        for (int j = 0; j < 2; j++) {
            bf16x8 bg = *(const bf16x8*)&Bg[(wn * 32 + j * 16 + l16) * 32 + quad * 8];
            bf16x8 bu = *(const bf16x8*)&Bu[(wn * 32 + j * 16 + l16) * 32 + quad * 8];
#pragma unroll
            for (int i = 0; i < 4; i++) {
                accg[i][j] = __builtin_amdgcn_mfma_f32_16x16x32_bf16(a[i], bg, accg[i][j], 0, 0, 0);
                accu[i][j] = __builtin_amdgcn_mfma_f32_16x16x32_bf16(a[i], bu, accu[i][j], 0, 0, 0);
            }
        }
    }
    // epilogue: h = silu(g)*u -> bf16
#pragma unroll
    for (int i = 0; i < 4; i++) {
        const int mrow = mt * 128 + wm * 64 + i * 16 + quad * 4;
#pragma unroll
        for (int r = 0; r < 4; r++) {
            const int slot = mrow + r;
            if (slot < ne) {
                __bf16* hrow = hbuf + (size_t)(base + slot) * II + nt * 64 + wn * 32 + l16;
#pragma unroll
                for (int j = 0; j < 2; j++) {
                    float g = accg[i][j][r], u = accu[i][j][r];
                    float sgl = g / (1.0f + __expf(-g));
                    hrow[j * 16] = (__bf16)(sgl * u);
                }
            }
        }
    }
}

// ---------------------------------------------------------------- down proj
// Block tile 128(M) x 128(N), BK=32, wave tile 64x64, acc = 64 regs.
// Same prefetch pipeline + XCD panel swizzle (panel 1.44 MB fp32 < 4 MB L2).
__global__ __launch_bounds__(256, 3) void down_k(
        const float* __restrict__ Wd, const float* __restrict__ Wds,
        const __bf16* __restrict__ hbuf, float* __restrict__ out,
        const int* __restrict__ nlist, const int* __restrict__ offs,
        const int* __restrict__ tlist, const float* __restrict__ wlist) {
    const int e = blockIdx.z;
    const int ne = nlist[e];
    const int bx = blockIdx.x;                 // [0,256): 8 nt x 32 mt
    const int nt = bx & 7;                     // XCD = nt
    const int mt = bx >> 3;
    if (mt * 128 >= ne) return;
    const int base = offs[e];
    const float* wd = (e < EE) ? Wd + (size_t)e * HH * II : Wds;

    __shared__ __bf16 As[128 * 32];   // 8 KB
    __shared__ __bf16 Bs[128 * 32];   // 8 KB

    const int tid = threadIdx.x;
    const int arow0 = tid >> 2, c8 = (tid & 3) * 8;
    const int arow1 = arow0 + 64;
    const int cl0 = min(mt * 128 + arow0, ne - 1);
    const int cl1 = min(mt * 128 + arow1, ne - 1);
    const __bf16* aptr0 = hbuf + (size_t)(base + cl0) * II + c8;
    const __bf16* aptr1 = hbuf + (size_t)(base + cl1) * II + c8;
    const size_t boff0 = (size_t)(nt * 128 + arow0) * II + c8;
    const size_t boff1 = (size_t)(nt * 128 + arow1) * II + c8;

    const int wid = tid >> 6, lane = tid & 63;
    const int wm = wid >> 1, wn = wid & 1;
    const int l16 = lane & 15, quad = lane >> 4;

    f32x4v acc[4][4];
#pragma unroll
    for (int i = 0; i < 4; i++)
#pragma unroll
        for (int j = 0; j < 4; j++) acc[i][j] = (f32x4v)0.0f;

    // prefetch K-step 0
    bf16x8 aR0 = *(const bf16x8*)aptr0;
    bf16x8 aR1 = *(const bf16x8*)aptr1;
    f32x4v b00 = *(const f32x4v*)(wd + boff0);
    f32x4v b01 = *(const f32x4v*)(wd + boff0 + 4);
    f32x4v b10 = *(const f32x4v*)(wd + boff1);
    f32x4v b11 = *(const f32x4v*)(wd + boff1 + 4);

    for (int k0 = 0; k0 < II; k0 += 32) {
        bf16x8 bs0, bs1;
        bs0[0] = (__bf16)b00[0]; bs0[1] = (__bf16)b00[1]; bs0[2] = (__bf16)b00[2]; bs0[3] = (__bf16)b00[3];
        bs0[4] = (__bf16)b01[0]; bs0[5] = (__bf16)b01[1]; bs0[6] = (__bf16)b01[2]; bs0[7] = (__bf16)b01[3];
        bs1[0] = (__bf16)b10[0]; bs1[1] = (__bf16)b10[1]; bs1[2] = (__bf16)b10[2]; bs1[3] = (__bf16)b10[3];
        bs1[4] = (__bf16)b11[0]; bs1[5] = (__bf16)b11[1]; bs1[6] = (__bf16)b11[2]; bs1[7] = (__bf16)b11[3];
        __syncthreads();
        *(bf16x8*)&As[arow0 * 32 + c8] = aR0;
        *(bf16x8*)&As[arow1 * 32 + c8] = aR1;
        *(bf16x8*)&Bs[arow0 * 32 + c8] = bs0;
        *(bf16x8*)&Bs[arow1 * 32 + c8] = bs1;
        if (k0 + 32 < II) {
            aR0 = *(const bf16x8*)(aptr0 + k0 + 32);
            aR1 = *(const bf16x8*)(aptr1 + k0 + 32);
            b00 = *(const f32x4v*)(wd + boff0 + k0 + 32);
            b01 = *(const f32x4v*)(wd + boff0 + k0 + 36);
            b10 = *(const f32x4v*)(wd + boff1 + k0 + 32);
            b11 = *(const f32x4v*)(wd + boff1 + k0 + 36);
        }
        __syncthreads();
        bf16x8 a[4];
#pragma unroll
        for (int i = 0; i < 4; i++)
            a[i] = *(const bf16x8*)&As[(wm * 64 + i * 16 + l16) * 32 + quad * 8];
#pragma unroll
        for (int j = 0; j < 4; j++) {
            bf16x8 b = *(const bf16x8*)&Bs[(wn * 64 + j * 16 + l16) * 32 + quad * 8];
#pragma unroll
            for (int i = 0; i < 4; i++)
                acc[i][j] = __builtin_amdgcn_mfma_f32_16x16x32_bf16(a[i], b, acc[i][j], 0, 0, 0);
        }
    }
    // epilogue: out[token] += w_slot * acc
#pragma unroll
    for (int i = 0; i < 4; i++) {
        const int mrow = mt * 128 + wm * 64 + i * 16 + quad * 4;
#pragma unroll
        for (int r = 0; r < 4; r++) {
            const int slot = mrow + r;
            if (slot < ne) {
                const int idx = base + slot;
                const int tok = tlist[idx];
                const float w = wlist[idx];
                float* orow = out + (size_t)tok * HH + nt * 128 + wn * 64 + l16;
#pragma unroll
                for (int j = 0; j < 4; j++)
                    atomicAdd(&orow[j * 16], w * acc[i][j][r]);
            }
        }
    }
}

// ---------------------------------------------------------------- launch
extern "C" void kernel_launch(void* const* d_in, const int* in_sizes, int n_in,
                              void* d_out, int out_size, void* d_ws, size_t ws_size,
                              hipStream_t stream) {
    const float* x   = (const float*)d_in[0];
    const float* Wgs = (const float*)d_in[1];
    const float* Wus = (const float*)d_in[2];
    const float* Wds = (const float*)d_in[3];
    const float* Wg  = (const float*)d_in[4];
    const float* Wu  = (const float*)d_in[5];
    const float* Wd  = (const float*)d_in[6];
    const float* Wr  = (const float*)d_in[7];
    float* out = (float*)d_out;                        // [NTOK][HH]
    float* logits = out + (size_t)NTOK * HH;           // [NTOK][EE]

    // workspace layout (~78 MB)
    char* ws = (char*)d_ws;
    __bf16* hbuf = (__bf16*)ws;                                    // NSLOT*II bf16
    __bf16* xb   = (__bf16*)(ws + (size_t)NSLOT * II * 2);         // NTOK*HH bf16
    char* meta   = ws + (size_t)NSLOT * II * 2 + (size_t)NTOK * HH * 2;
    int* counts = (int*)meta;            // 8
    int* cursor = counts + 8;            // 8
    int* nlist  = cursor + 8;            // 8
    int* offs   = nlist + 8;             // 8
    int* sel    = offs + 8;              // 2*NTOK
    int* tlist  = sel + 2 * NTOK;        // NSLOT
    float* wtop = (float*)(tlist + NSLOT);   // 2*NTOK
    float* wlist = wtop + 2 * NTOK;          // NSLOT

    hipMemsetAsync(counts, 0, 8 * sizeof(int), stream);
    hipMemsetAsync(out, 0, (size_t)NTOK * HH * sizeof(float), stream);

    cvt_x<<<1024, 256, 0, stream>>>(x, xb);
    router_k<<<NTOK / 4, 256, 0, stream>>>(x, Wr, logits, counts, sel, wtop, tlist, wlist);
    finalize_k<<<1, 64, 0, stream>>>(counts, cursor, nlist, offs);
    scatter_k<<<NTOK / 256, 256, 0, stream>>>(sel, wtop, cursor, tlist, wlist);
    gateup_k<<<dim3(1536, 1, EE + 1), 256, 0, stream>>>(Wg, Wu, Wgs, Wus, xb, hbuf,
                                                        nlist, offs, tlist);
    down_k<<<dim3(256, 1, EE + 1), 256, 0, stream>>>(Wd, Wds, hbuf, out,
                                                     nlist, offs, tlist, wlist);
}